// Round 6
// baseline (359.335 us; speedup 1.0000x reference)
//
#include <hip/hip_runtime.h>
#include <hip/hip_bf16.h>
#include <math.h>

// Problem constants
#define BATCH 16
#define L1 32
#define L2 128
#define DEC 512
#define MEM 512
#define TOPN 50
#define NROWS (BATCH * L1 * L2)   // 65536 word rows
#define NBQ (BATCH * L1)          // 512 (b,q) rows

typedef short short8 __attribute__((ext_vector_type(8)));
typedef float f32x16 __attribute__((ext_vector_type(16)));

// ---------------- ws layout (floats) ----------------
#define WS_WP     0          // perm bf16 Wm : 32768 slots x 16B = floats [0,131072)
#define WS_WP2    131072     // perm bf16 Wm2
#define WS_BIAS1  262144
#define WS_BIAS2  270336
#define WS_DOCSC  278528     // doc scores [512] -> end 279040 (~1.07 MB total)

// packed pair via v_cvt_pk_bf16_f32
__device__ __forceinline__ unsigned int pkbf(float a, float b) {
    __hip_bfloat162 h = __float22bfloat162_rn(float2{a, b});
    union { __hip_bfloat162 h; unsigned int u; } c{h};
    return c.u;
}

__device__ __forceinline__ float fast_tanh(float x) {
    return 1.f - 2.f / (__expf(2.f * x) + 1.f);
}

// ============ kernel 0 (merged setup): permute Wm/Wm2 + bias1/bias2 + zero ctx ============
// permute slot s (16B) holds Wm[d][k..k+7] bf16: s = C*1024 + nt*64 + k8*32 + n
//   d = nt*32+n ; k = C*16 + k8*8      (layout HW-verified in R3)
__global__ __launch_bounds__(256) void setup_kernel(
    const float* __restrict__ Wm, const float* __restrict__ Wm2,
    unsigned short* __restrict__ Wp, unsigned short* __restrict__ Wp2,
    const float* __restrict__ dec, const float* __restrict__ topic,
    const float* __restrict__ Wd, const float* __restrict__ Wt,
    const float* __restrict__ Wd2, const float* __restrict__ Wt2,
    float* __restrict__ bias1, float* __restrict__ bias2,
    float* __restrict__ ctx_out)
{
    if (blockIdx.x < 128) {
        int s = blockIdx.x * 256 + threadIdx.x;     // 0..32767
        int C = s >> 10;
        int u = s & 1023;
        int nt = u >> 6, k8 = (u >> 5) & 1, n_in = u & 31;
        int d = nt * 32 + n_in;
        int k = C * 16 + k8 * 8;

        const float* src = Wm + (size_t)d * DEC + k;
        uint4 v;
        v.x = pkbf(src[0], src[1]); v.y = pkbf(src[2], src[3]);
        v.z = pkbf(src[4], src[5]); v.w = pkbf(src[6], src[7]);
        ((uint4*)Wp)[s] = v;

        const float* src2 = Wm2 + (size_t)d * DEC + k;
        uint4 w;
        w.x = pkbf(src2[0], src2[1]); w.y = pkbf(src2[2], src2[3]);
        w.z = pkbf(src2[4], src2[5]); w.w = pkbf(src2[6], src2[7]);
        ((uint4*)Wp2)[s] = w;
    } else if (blockIdx.x < 160) {
        int idx = (blockIdx.x - 128) * 256 + threadIdx.x;   // 8192
        int b = idx >> 9, d = idx & 511;
        float a1 = 0.f, a2 = 0.f;
        const float* db = dec + b * DEC;
        const float* w1 = Wd + (size_t)d * DEC;
        const float* w2 = Wd2 + (size_t)d * DEC;
#pragma unroll 4
        for (int k = 0; k < DEC; ++k) {
            float x = db[k];
            a1 = fmaf(x, w1[k], a1);
            a2 = fmaf(x, w2[k], a2);
        }
        const float* tb = topic + b * TOPN;
        const float* t1 = Wt + (size_t)d * TOPN;
        const float* t2 = Wt2 + (size_t)d * TOPN;
#pragma unroll 2
        for (int t = 0; t < TOPN; ++t) {
            float x = tb[t];
            a1 = fmaf(x, t1[t], a1);
            a2 = fmaf(x, t2[t], a2);
        }
        bias1[idx] = a1;
        bias2[idx] = a2;
    } else {
        // zero ctx accumulator region of d_out (8192 floats)
        int i = (blockIdx.x - 160) * 256 + threadIdx.x;   // 0..1023
        float4 z = {0.f, 0.f, 0.f, 0.f};
        ((float4*)ctx_out)[i * 2] = z;
        ((float4*)ctx_out)[i * 2 + 1] = z;
    }
}

// ============ doc score kernel (R3-verified MFMA kernel, 8 blocks) ============
__global__ __launch_bounds__(256) void score_mfma_kernel(
    const float* __restrict__ X,            // [nrows][512]
    const unsigned short* __restrict__ Wp,  // permuted bf16 weights
    const float* __restrict__ Wv,           // [512]
    const float* __restrict__ bias,         // [16][512]
    float* __restrict__ scores,             // [nrows]
    int bshift)                             // batch = row >> bshift
{
    __shared__ __align__(16) short lsA[256 * 8];
    __shared__ __align__(16) short lsB[2048 * 8];
    __shared__ float red[4][64];

    const int tid = threadIdx.x;
    const int lane = tid & 63;
    const int wid = tid >> 6;
    const int row0 = blockIdx.x * 64;

    const int srow = tid >> 2;
    const int kslot = tid & 3;
    const int sA = ((kslot >> 1) * 2 + (srow >> 5)) * 64 + (kslot & 1) * 32 + (srow & 31);
    const float4* xs4 = (const float4*)(X + (size_t)(row0 + srow) * DEC) + kslot * 2;

    const uint4* bsrc = (const uint4*)Wp + (size_t)wid * 512 + lane;

    f32x16 acc[8];
#pragma unroll
    for (int t = 0; t < 8; ++t)
        acc[t] = (f32x16){0.f,0.f,0.f,0.f, 0.f,0.f,0.f,0.f, 0.f,0.f,0.f,0.f, 0.f,0.f,0.f,0.f};

    const short8* lA = (const short8*)lsA;
    const short8* lB = (const short8*)lsB;

    for (int it = 0; it < 16; ++it) {
        uint4 bv[8];
#pragma unroll
        for (int i = 0; i < 8; ++i) bv[i] = bsrc[i * 64];
        bsrc += 2048;
#pragma unroll
        for (int i = 0; i < 8; ++i)
            *((uint4*)&lsB[((size_t)wid * 512 + i * 64 + lane) * 8]) = bv[i];

        float4 xv0 = xs4[0];
        float4 xv1 = xs4[1];
        xs4 += 8;
        union { unsigned int u[4]; short8 s; } xb;
        xb.u[0] = pkbf(xv0.x, xv0.y); xb.u[1] = pkbf(xv0.z, xv0.w);
        xb.u[2] = pkbf(xv1.x, xv1.y); xb.u[3] = pkbf(xv1.z, xv1.w);
        *((short8*)&lsA[sA * 8]) = xb.s;

        __syncthreads();

#pragma unroll
        for (int c = 0; c < 2; ++c) {
            short8 a0 = lA[(c * 2 + 0) * 64 + lane];
            short8 a1 = lA[(c * 2 + 1) * 64 + lane];
            short8 b0 = lB[c * 1024 + (wid * 4 + 0) * 64 + lane];
            short8 b1 = lB[c * 1024 + (wid * 4 + 1) * 64 + lane];
            short8 b2 = lB[c * 1024 + (wid * 4 + 2) * 64 + lane];
            short8 b3 = lB[c * 1024 + (wid * 4 + 3) * 64 + lane];
            acc[0] = __builtin_amdgcn_mfma_f32_32x32x16_bf16(a0, b0, acc[0], 0, 0, 0);
            acc[1] = __builtin_amdgcn_mfma_f32_32x32x16_bf16(a0, b1, acc[1], 0, 0, 0);
            acc[2] = __builtin_amdgcn_mfma_f32_32x32x16_bf16(a0, b2, acc[2], 0, 0, 0);
            acc[3] = __builtin_amdgcn_mfma_f32_32x32x16_bf16(a0, b3, acc[3], 0, 0, 0);
            acc[4] = __builtin_amdgcn_mfma_f32_32x32x16_bf16(a1, b0, acc[4], 0, 0, 0);
            acc[5] = __builtin_amdgcn_mfma_f32_32x32x16_bf16(a1, b1, acc[5], 0, 0, 0);
            acc[6] = __builtin_amdgcn_mfma_f32_32x32x16_bf16(a1, b2, acc[6], 0, 0, 0);
            acc[7] = __builtin_amdgcn_mfma_f32_32x32x16_bf16(a1, b3, acc[7], 0, 0, 0);
        }
        __syncthreads();
    }

    const int col = lane & 31;
    const int h = lane >> 5;
    float wv[4], bs[2][4];
    const int b0i = (row0) >> bshift;
    const int b1i = (row0 + 32) >> bshift;
#pragma unroll
    for (int nt = 0; nt < 4; ++nt) {
        int d = wid * 128 + nt * 32 + col;
        wv[nt] = Wv[d];
        bs[0][nt] = bias[b0i * DEC + d];
        bs[1][nt] = bias[b1i * DEC + d];
    }

#pragma unroll
    for (int mt = 0; mt < 2; ++mt) {
#pragma unroll
        for (int r = 0; r < 16; ++r) {
            float p = 0.f;
#pragma unroll
            for (int nt = 0; nt < 4; ++nt) {
                float x = acc[mt * 4 + nt][r] + bs[mt][nt];
                p = fmaf(wv[nt], fast_tanh(x), p);
            }
            p += __shfl_xor(p, 16);
            p += __shfl_xor(p, 8);
            p += __shfl_xor(p, 4);
            p += __shfl_xor(p, 2);
            p += __shfl_xor(p, 1);
            if (col == mt * 16 + r) {
                int row_in = (r & 3) + 8 * (r >> 2) + 4 * h;
                red[wid][mt * 32 + row_in] = p;
            }
        }
    }
    __syncthreads();
    if (tid < 64)
        scores[row0 + tid] = red[0][tid] + red[1][tid] + red[2][tid] + red[3][tid];
}

// ============ fused word kernel: doc-softmax + scores (MFMA) + softmax + rescale + ctx ============
// Block = one (b,q): 128 rows. 512 thr / 8 waves; wave w owns d [w*64,(w+1)*64).
// K in 2 chunks of 256 staged whole into 2x64KB LDS -> only 2 barriers in the K path
// (each barrier's vmcnt(0) drain is BW-paced, not latency-paced: 16x16B loads/thread in flight).
// Context computed from the bf16 LDS image (no global X re-read).
__global__ __launch_bounds__(512) void fused_word_kernel(
    const float* __restrict__ X,            // word_memory [65536][512]
    const unsigned short* __restrict__ Wp,  // permuted bf16 Wm
    const float* __restrict__ Wv,           // [512]
    const float* __restrict__ bias1,        // [16][512]
    const float* __restrict__ doc_scores,   // [512]
    const int* __restrict__ doc_mask,       // [512]
    const int* __restrict__ word_mask,      // [65536]
    float* __restrict__ rescaled_out,       // d_out + 8192
    float* __restrict__ ctx_out)            // d_out [16][512], pre-zeroed, atomic
{
    __shared__ __align__(16) short lsA[2][32768];   // 2 x 64KB: full 128x256 bf16 A-chunk each
    __shared__ float red[8][128];
    __shared__ float sS[128];
    __shared__ float rmax2[2], rsum2[2];
    __shared__ float s_dattn;

    const int tid = threadIdx.x;
    const int lane = tid & 63;
    const int wid = tid >> 6;          // 0..7
    const int bq = blockIdx.x;         // 0..511
    const int r0 = bq * L2;            // first word row
    const int b = bq >> 5;
    const int q = bq & 31;

    // ---- doc softmax for this block's (b,q): one scalar ----
    if (tid < 32) {
        int di = b * 32 + tid;
        float dsv = doc_scores[di];
        if (doc_mask[di] == 0) dsv = -INFINITY;
        float mx = dsv;
#pragma unroll
        for (int o = 1; o <= 16; o <<= 1) mx = fmaxf(mx, __shfl_xor(mx, o));
        float e = __expf(dsv - mx);
        float sum = e;
#pragma unroll
        for (int o = 1; o <= 16; o <<= 1) sum += __shfl_xor(sum, o);
        if (tid == q) s_dattn = e / sum;
    }

    // ---- staging map: thread -> (row r, k-quad kq) ----
    const int r = tid >> 2;            // 0..127
    const int kq = tid & 3;            // float4 within 16-k sub-chunk
    const int mt_s = r >> 5;
    const int rl_s = r & 31;
    const int lpart = (kq >> 1) * 32 + rl_s;   // lane part of slot
    const int j0 = (kq & 1) * 4;               // short offset in slot
    const float4* xrow = (const float4*)(X + (size_t)(r0 + r) * DEC);

    const uint4* Bp = (const uint4*)Wp;
    const int boff = wid * 128 + lane;

    f32x16 acc[8];   // [mt*2 + nt]
#pragma unroll
    for (int t = 0; t < 8; ++t)
        acc[t] = (f32x16){0.f,0.f,0.f,0.f, 0.f,0.f,0.f,0.f, 0.f,0.f,0.f,0.f, 0.f,0.f,0.f,0.f};

    // B rolling prefetch (depth 2), continuous over C = 0..31
    uint4 ub0[2], ub1[2];
#pragma unroll
    for (int i = 0; i < 2; ++i) {
        ub0[i] = Bp[i * 1024 + boff];
        ub1[i] = Bp[i * 1024 + boff + 64];
    }

#pragma unroll
    for (int kc = 0; kc < 2; ++kc) {
        // ---- stage chunk kc (256 k) into lsA[kc]: 16 x 16B loads/thread, 2 waves of 8 ----
#pragma unroll
        for (int hf = 0; hf < 2; ++hf) {
            float4 va[8];
#pragma unroll
            for (int i = 0; i < 8; ++i)
                va[i] = xrow[kc * 64 + hf * 32 + i * 4 + kq];
#pragma unroll
            for (int i = 0; i < 8; ++i) {
                int c = hf * 8 + i;
                uint2 w2;
                w2.x = pkbf(va[i].x, va[i].y);
                w2.y = pkbf(va[i].z, va[i].w);
                *(uint2*)&lsA[kc][((c * 4 + mt_s) * 64 + lpart) * 8 + j0] = w2;
            }
        }
        __syncthreads();

        // ---- 16 barrier-free MFMA sub-iterations ----
        const short8* lAp = (const short8*)lsA[kc];
#pragma unroll
        for (int c = 0; c < 16; ++c) {
            const int p = c & 1;
            short8 a0 = lAp[(c * 4 + 0) * 64 + lane];
            short8 a1 = lAp[(c * 4 + 1) * 64 + lane];
            short8 a2 = lAp[(c * 4 + 2) * 64 + lane];
            short8 a3 = lAp[(c * 4 + 3) * 64 + lane];
            union { uint4 u; short8 s; } cb0{ub0[p]}, cb1{ub1[p]};
            // roll B: load C+2 (wraps harmlessly at the very end)
            const int C2 = (kc * 16 + c + 2) & 31;
            uint4 nb0 = Bp[C2 * 1024 + boff];
            uint4 nb1 = Bp[C2 * 1024 + boff + 64];
            acc[0] = __builtin_amdgcn_mfma_f32_32x32x16_bf16(a0, cb0.s, acc[0], 0, 0, 0);
            acc[1] = __builtin_amdgcn_mfma_f32_32x32x16_bf16(a0, cb1.s, acc[1], 0, 0, 0);
            acc[2] = __builtin_amdgcn_mfma_f32_32x32x16_bf16(a1, cb0.s, acc[2], 0, 0, 0);
            acc[3] = __builtin_amdgcn_mfma_f32_32x32x16_bf16(a1, cb1.s, acc[3], 0, 0, 0);
            acc[4] = __builtin_amdgcn_mfma_f32_32x32x16_bf16(a2, cb0.s, acc[4], 0, 0, 0);
            acc[5] = __builtin_amdgcn_mfma_f32_32x32x16_bf16(a2, cb1.s, acc[5], 0, 0, 0);
            acc[6] = __builtin_amdgcn_mfma_f32_32x32x16_bf16(a3, cb0.s, acc[6], 0, 0, 0);
            acc[7] = __builtin_amdgcn_mfma_f32_32x32x16_bf16(a3, cb1.s, acc[7], 0, 0, 0);
            ub0[p] = nb0; ub1[p] = nb1;
        }
        // no barrier needed here: next stage writes lsA[kc^1], different buffer
    }

    // ---- epilogue: tanh + Wv partial over this wave's 64 d ----
    // C/D layout (32x32, HW-verified): col = lane&31, row_in = (r&3) + 8*(r>>2) + 4*(lane>>5)
    const int col = lane & 31;
    const int h = lane >> 5;
    float wv0, wv1, bs0, bs1;
    {
        int d0 = wid * 64 + col;
        int d1 = wid * 64 + 32 + col;
        wv0 = Wv[d0]; wv1 = Wv[d1];
        bs0 = bias1[b * DEC + d0]; bs1 = bias1[b * DEC + d1];
    }
#pragma unroll
    for (int mt = 0; mt < 4; ++mt) {
#pragma unroll
        for (int rr = 0; rr < 16; ++rr) {
            float p = fmaf(wv0, fast_tanh(acc[mt * 2 + 0][rr] + bs0),
                           wv1 * fast_tanh(acc[mt * 2 + 1][rr] + bs1));
            p += __shfl_xor(p, 16);
            p += __shfl_xor(p, 8);
            p += __shfl_xor(p, 4);
            p += __shfl_xor(p, 2);
            p += __shfl_xor(p, 1);
            if (col == rr) {
                int row_in = (rr & 3) + 8 * (rr >> 2) + 4 * h;
                red[wid][mt * 32 + row_in] = p;
            }
        }
    }
    __syncthreads();

    // ---- block softmax over 128 words (threads 0..127) ----
    float e = 0.f, sv = 0.f;
    if (tid < 128) {
        sv = red[0][tid] + red[1][tid] + red[2][tid] + red[3][tid]
           + red[4][tid] + red[5][tid] + red[6][tid] + red[7][tid];
        if (word_mask[r0 + tid] == 0) sv = -INFINITY;
        float mx = sv;
#pragma unroll
        for (int o = 1; o <= 32; o <<= 1) mx = fmaxf(mx, __shfl_xor(mx, o));
        if (lane == 0) rmax2[wid] = mx;
    }
    __syncthreads();
    if (tid < 128) {
        float mx = fmaxf(rmax2[0], rmax2[1]);
        e = __expf(sv - mx);
        float sum = e;
#pragma unroll
        for (int o = 1; o <= 32; o <<= 1) sum += __shfl_xor(sum, o);
        if (lane == 0) rsum2[wid] = sum;
    }
    __syncthreads();
    if (tid < 128) {
        float sum = rsum2[0] + rsum2[1];
        float resc = s_dattn * (e / sum);
        sS[tid] = resc;
        rescaled_out[r0 + tid] = resc;
    }
    __syncthreads();

    // ---- context from the bf16 LDS image: thread t owns column m = t ----
    {
        const int m = tid;
        const int kc = m >> 8;
        const int mm = m & 255;
        const int c = mm >> 4;
        const int k8 = (mm >> 3) & 1;
        const int j = mm & 7;
        const unsigned short* Lp = (const unsigned short*)lsA[kc];
        const int base = (c * 4) * 64 * 8 + (k8 * 32) * 8 + j;
        float s = 0.f;
#pragma unroll 4
        for (int w = 0; w < 128; ++w) {
            unsigned short u = Lp[base + ((w >> 5) * 64 + (w & 31)) * 8];
            union { unsigned int ui; float f; } cv{(unsigned int)u << 16};
            s = fmaf(sS[w], cv.f, s);
        }
        atomicAdd(ctx_out + (size_t)b * MEM + m, s);
    }
}

extern "C" void kernel_launch(void* const* d_in, const int* in_sizes, int n_in,
                              void* d_out, int out_size, void* d_ws, size_t ws_size,
                              hipStream_t stream) {
    const float* decoder_state = (const float*)d_in[0];
    const float* doc_memory    = (const float*)d_in[1];
    const float* word_memory   = (const float*)d_in[2];
    const float* topic_dist    = (const float*)d_in[3];
    const int*   doc_mask      = (const int*)d_in[4];
    const int*   word_mask     = (const int*)d_in[5];
    const float* Wv  = (const float*)d_in[6];
    const float* Wd  = (const float*)d_in[7];
    const float* Wt  = (const float*)d_in[8];
    const float* Wm  = (const float*)d_in[9];
    const float* Wv2 = (const float*)d_in[10];
    const float* Wd2 = (const float*)d_in[11];
    const float* Wt2 = (const float*)d_in[12];
    const float* Wm2 = (const float*)d_in[13];

    float* ws = (float*)d_ws;
    unsigned short* Wp  = (unsigned short*)(ws + WS_WP);
    unsigned short* Wp2 = (unsigned short*)(ws + WS_WP2);
    float* bias1       = ws + WS_BIAS1;
    float* bias2       = ws + WS_BIAS2;
    float* doc_scores  = ws + WS_DOCSC;

    float* ctx_out      = (float*)d_out;                 // [16][512]
    float* rescaled_out = (float*)d_out + BATCH * MEM;   // [16][32][128]

    setup_kernel<<<164, 256, 0, stream>>>(Wm, Wm2, Wp, Wp2,
                                          decoder_state, topic_dist,
                                          Wd, Wt, Wd2, Wt2, bias1, bias2, ctx_out);
    score_mfma_kernel<<<NBQ / 64, 256, 0, stream>>>(doc_memory, Wp2, Wv2, bias2, doc_scores, 5);
    fused_word_kernel<<<NBQ, 512, 0, stream>>>(word_memory, Wp, Wv, bias1,
                                               doc_scores, doc_mask, word_mask,
                                               rescaled_out, ctx_out);
}